// Round 9
// baseline (50.803 us; speedup 1.0000x reference)
//
#include <hip/hip_runtime.h>
#include <math.h>

// F0Resonance — bit-exact replication of XLA's tiled-scan cumsum (verified r6/r8).
// jnp.cumsum lowers via ReduceWindowRewriter, base B=16: [32768]->[2048,16],
// sequential fp32 inner scans, recursive carry scan (2048->128->8), one fp32
// combine-add per level. For constant increment x:
//   A0[i]=seq(i+1,x), B1=seq(.,T0), B2=seq(.,T1), B3=seq(.,T2)
//   phase(j) = fl( A0[j&15] + P1((j>>4)-1) ),  P1(m)=fl(B1[m&15]+P2(..))
// hipcc contracts mul+add into FMA (fast-honor-pragmas) which perturbs the
// phase chain by 1 ulp -> 0.03 rad at n=32768 (r7 failure) -> contract(off),
// plus asm keep-barriers on the 5 scalar-chain values (cheap: once/thread).
// sin(exact fp32 phase): fp32 Cody-Waite (kq*C1 exact in FMA for kq<2^17;
// residual ~1e-5 rad) + hw v_sin_f32 (input in REVOLUTIONS).
//
// r8->r9 perf: drop the 128KB s_osc staging (its ds_write_b128 was a
// full-wave bank pileup: lane stride 128B -> bank independent of lane;
// 1.88M conflict cycles) — keep 32 samples in registers (VGPR cap is 128
// at the grid-imposed 16 waves/CU; we were at 52), store thread-contiguous
// float4 (L2 write-combines), no barrier, no second pass.
#pragma clang fp contract(off)

constexpr int NSAMP = 32768;
constexpr int NROWS = 256;   // B*E = 4*64
constexpr int NOCT  = 16;
constexpr int TPB   = 1024;

// hard barrier against cross-statement fusion on the scalar chain
__device__ __forceinline__ float keepf(float x) {
  asm volatile("" : "+v"(x));
  return x;
}

__global__ __launch_bounds__(TPB, 4) void f0res_kernel(
    const float* __restrict__ f0_in,
    const float* __restrict__ dec_in,
    const float* __restrict__ fs_in,
    float* __restrict__ out)
{
  const int row = blockIdx.x;
  const int t   = threadIdx.x;

  __shared__ float s_tab[NOCT][64];  // [0:16)=A0 [16:32)=B1 [32:48)=B2 [48:56)=B3
  __shared__ float s_w[NOCT];
  __shared__ float s_red[TPB / 64];

  // ---- fp32 scalar chain (reference roundings; contraction pinned off) ----
  const float f0a = fabsf(f0_in[row]);
  const float dcc = dec_in[row];
  const float fsv = fs_in[row];

  const float MIN_F = (float)(20.0 / 11025.0);
  const float RNG_F = (float)(3000.0 / 11025.0 - 20.0 / 11025.0);
  const float c1s   = keepf(f0a * RNG_F);       // fl32 mul
  const float c2s   = keepf(MIN_F + c1s);       // fl32 add (NOT fma)
  const float f0ang = keepf(c2s * (float)M_PI); // fl32 mul

  const float sg    = 1.0f / (1.0f + expf(-dcc));
  const float dvv   = 1.0f / (1.0f + expf(-sg));   // double sigmoid
  const float dvr   = keepf(dvv * 0.9405f);        // (1-0.01)*0.95
  const float decay = keepf(0.01f + dvr);          // fl32 add (NOT fma)
  const float ldv   = logf(decay + 1e-12f);

  // ---- builder: lane k builds octave k's tables + weight ----
  if (t < NOCT) {
    const int k = t;
    float fac = 0.0f;
    for (int j = 0; j <= k; ++j) fac = fac + fsv;   // 16-elem seq cumsum
    const float x = keepf(f0ang * fac);
    float* tab = s_tab[k];
    float a = 0.0f;
#pragma unroll
    for (int i = 0; i < 16; ++i) { a = a + x;  tab[i]      = a; }
    const float T0 = a; a = 0.0f;
#pragma unroll
    for (int i = 0; i < 16; ++i) { a = a + T0; tab[16 + i] = a; }
    const float T1 = a; a = 0.0f;
#pragma unroll
    for (int i = 0; i < 16; ++i) { a = a + T1; tab[32 + i] = a; }
    const float T2 = a; a = 0.0f;
#pragma unroll
    for (int i = 0; i < 8;  ++i) { a = a + T2; tab[48 + i] = a; }
    float lc = 0.0f;
    for (int j = 0; j <= k; ++j) lc = lc + ldv;     // seq cumsum of log_decay
    s_w[k] = expf(lc);
  }
  __syncthreads();

  // Cody-Waite: 2pi = C1 + C2 (+~1e-10). C1 has a 7-bit mantissa, so
  // kq*C1 is exact inside the FMA for kq < 2^17 (here kq <= ~72e3).
  const float C1 = 6.28125f;
  const float C2 = (float)(6.283185307179586476925287 - 6.28125);
  const float INV2PI = (float)0.159154943091895335768883;

  // thread t owns samples j = 32t .. 32t+31 (two 16-sample scan windows)
  float osc[32];
#pragma unroll
  for (int e = 0; e < 32; ++e) osc[e] = 0.0f;

  const int m0 = 2 * t - 1;   // level-0 carry window index of half 0

#pragma unroll 2
  for (int k = 0; k < NOCT; ++k) {
    const float* tab = s_tab[k];
    // A0 into registers (4 x ds_read_b128, uniform address -> broadcast)
    float tv[16];
    *(float4*)&tv[0]  = ((const float4*)tab)[0];
    *(float4*)&tv[4]  = ((const float4*)tab)[1];
    *(float4*)&tv[8]  = ((const float4*)tab)[2];
    *(float4*)&tv[12] = ((const float4*)tab)[3];
    const float w = s_w[k];

    // carries P1(m0), P1(m0+1): exact fp32 per the tiled scan (pure adds)
    float carry[2];
#pragma unroll
    for (int h = 0; h < 2; ++h) {
      const int m = m0 + h;
      float c = 0.0f;
      if (m >= 0) {
        c = tab[16 + (m & 15)];
        const int m2 = (m >> 4) - 1;
        if (m2 >= 0) {
          float p2 = tab[32 + (m2 & 15)];
          const int m3 = (m2 >> 4) - 1;
          if (m3 >= 0) p2 = p2 + tab[48 + m3];
          c = c + p2;
        }
      }
      carry[h] = c;
    }

#pragma unroll
    for (int e = 0; e < 32; ++e) {
      const float p = tv[e & 15] + carry[e >> 4];   // exact ref phase bits
      // fp32 Cody-Waite mod 2pi -> revolutions (arg err ~1e-5 rad)
      const float kq = rintf(p * INV2PI);
      float r = __builtin_fmaf(-kq, C1, p);         // exact product in fma
      r = __builtin_fmaf(-kq, C2, r);
      const float fr = r * INV2PI;
      float sv;
      asm("v_sin_f32 %0, %1" : "=v"(sv) : "v"(fr)); // sin(fr * 2pi)
      // fma vs ref's mul+add: <=6e-8/term on the OUTPUT sum (phase bits
      // untouched); total ~1e-6 << bf16 compare quantum 0.0039.
      osc[e] = __builtin_fmaf(w, sv, osc[e]);
    }
  }

  // ---- block max reduction (order-independent) ----
  float lmax = 0.0f;
#pragma unroll
  for (int e = 0; e < 32; ++e) lmax = fmaxf(lmax, fabsf(osc[e]));
#pragma unroll
  for (int off = 32; off >= 1; off >>= 1)
    lmax = fmaxf(lmax, __shfl_xor(lmax, off, 64));
  if ((t & 63) == 0) s_red[t >> 6] = lmax;
  __syncthreads();
  float mx = s_red[0];
#pragma unroll
  for (int i = 1; i < TPB / 64; ++i) mx = fmaxf(mx, s_red[i]);
  const float inv = 1.0f / (mx + 1e-8f);

  // ---- scaled stores: 8 x float4 per thread (L2 write-combines) ----
  float4* o4 = (float4*)(out + (size_t)row * NSAMP + 32 * t);
#pragma unroll
  for (int q = 0; q < 8; ++q) {
    float4 v;
    v.x = osc[4 * q + 0] * inv;
    v.y = osc[4 * q + 1] * inv;
    v.z = osc[4 * q + 2] * inv;
    v.w = osc[4 * q + 3] * inv;
    o4[q] = v;
  }
}

extern "C" void kernel_launch(void* const* d_in, const int* in_sizes, int n_in,
                              void* d_out, int out_size, void* d_ws, size_t ws_size,
                              hipStream_t stream) {
    const float* f0  = (const float*)d_in[0];  // (4,64,1)
    const float* dcc = (const float*)d_in[1];  // decay_coefficients
    // d_in[2] = phase_offsets: computed-but-unused in the reference
    const float* fsp = (const float*)d_in[3];  // freq_spacing
    float* out = (float*)d_out;                // (4,64,32768) fp32

    f0res_kernel<<<NROWS, TPB, 0, stream>>>(f0, dcc, fsp, out);
}